// Round 19
// baseline (119.230 us; speedup 1.0000x reference)
//
#include <hip/hip_runtime.h>
#include <hip/hip_bf16.h>
#include <stdint.h>

#define T_SEQ 1024
#define C_DIM 1024
#define NH 16
#define DH 64

typedef __attribute__((ext_vector_type(8))) __bf16 bf16x8;
typedef __attribute__((ext_vector_type(8))) uint16_t u16x8;
typedef __attribute__((ext_vector_type(4))) float f32x4;

__device__ __forceinline__ uint16_t f2bf(float f) {
    union { float f; uint32_t u; } v; v.f = f;
    uint32_t u = v.u;
    return (uint16_t)((u + 0x7FFFu + ((u >> 16) & 1u)) >> 16);
}
__device__ __forceinline__ float bf2f(uint16_t b) {
    union { uint32_t u; float f; } v; v.u = ((uint32_t)b) << 16; return v.f;
}

// ---------- fused prep: cast x (blocks 0-2047) + transpose 4 weights (2048-6143) ----------
__global__ void k_prep(const float* __restrict__ x,
                       const float* __restrict__ W0, const float* __restrict__ W1,
                       const float* __restrict__ W2, const float* __restrict__ W3,
                       uint16_t* __restrict__ xb, uint16_t* __restrict__ wout) {
    const int gid = blockIdx.x;
    if (gid < 2048) {
        int i = gid * 256 + threadIdx.x;
        const int st = 2048 * 256;
#pragma unroll
        for (int it = 0; it < 2; it++, i += st) {
            float4 v = reinterpret_cast<const float4*>(x)[i];
            ushort4 o;
            o.x = f2bf(v.x); o.y = f2bf(v.y); o.z = f2bf(v.z); o.w = f2bf(v.w);
            reinterpret_cast<ushort4*>(xb)[i] = o;
        }
        return;
    }
    __shared__ float tile[32][33];
    const int id2 = gid - 2048;
    const int z = id2 >> 10;
    const int by = ((id2 >> 5) & 31) * 32;   // k block
    const int bx = (id2 & 31) * 32;          // n block
    const float* in = (z == 0) ? W0 : (z == 1) ? W1 : (z == 2) ? W2 : W3;
    uint16_t* o = wout + ((size_t)z << 20);
    const int tx = threadIdx.x & 31, ty = threadIdx.x >> 5;
#pragma unroll
    for (int i = 0; i < 4; i++)
        tile[ty + i * 8][tx] = in[(size_t)(by + ty + i * 8) * C_DIM + bx + tx];
    __syncthreads();
#pragma unroll
    for (int i = 0; i < 4; i++)
        o[(size_t)(bx + ty + i * 8) * C_DIM + by + tx] = f2bf(tile[tx][ty + i * 8]);
}

// ---------- V column mean (uniform-softmax fallback for fully-masked rows) ----------
__global__ void k_vmean(const uint16_t* __restrict__ Vt, float* __restrict__ Vmean) {
    const int bh = blockIdx.x;
    const int tid = threadIdx.x;
    const int d = tid >> 2, part = tid & 3;
    const uint16_t* src = Vt + ((size_t)bh * DH + d) * T_SEQ + part * 256;
    float s = 0.f;
#pragma unroll
    for (int i = 0; i < 32; i++) {
        u16x8 v = *reinterpret_cast<const u16x8*>(src + i * 8);
#pragma unroll
        for (int j = 0; j < 8; j++) s += bf2f(v[j]);
    }
    s += __shfl_xor(s, 1);
    s += __shfl_xor(s, 2);
    if (part == 0) Vmean[bh * DH + d] = s * (1.0f / 1024.0f);
}

// ---------- fused QKV GEMM: 64x128 tiles (1536 blocks = 6/CU), BK=32, swizzled ----------
// Wave w: rows [wm, wm+32) x cols [wn, wn+64); acc[2][4]. R18-validated structure.
__global__ __launch_bounds__(256) void k_gemm_qkv(const uint16_t* __restrict__ A,
                                                  const uint16_t* __restrict__ Bt,
                                                  const float* __restrict__ bq,
                                                  const float* __restrict__ bk,
                                                  const float* __restrict__ bv,
                                                  uint16_t* __restrict__ qb,
                                                  uint16_t* __restrict__ kb,
                                                  uint16_t* __restrict__ vt) {
    __shared__ uint16_t lA[64 * 32];
    __shared__ uint16_t lB[128 * 32];
    const int bm = blockIdx.x * 64;
    const int bn = blockIdx.y * 128;
    const int tid = threadIdx.x;
    const int lane = tid & 63;
    const int w = tid >> 6;
    const int wm = (w & 1) * 32;
    const int wn = (w >> 1) * 64;
    const int ko = (lane >> 4) * 8;
    const int rr = lane & 15;
    const int pos = ko ^ (((rr >> 1) & 3) << 3);

    f32x4 acc[2][4] = {};

    const int srow = tid >> 2;
    const int scol = (((tid & 3) ^ ((srow >> 1) & 3))) * 8;

    for (int kt = 0; kt < C_DIM; kt += 32) {
        // stage A 64x32 (1 issue/thread) + B 128x32 (2 issues/thread)
        {
            const uint16_t* ga = A + (size_t)(bm + (srow & 63)) * C_DIM + kt + scol;
            __builtin_amdgcn_global_load_lds(
                (const __attribute__((address_space(1))) void*)ga,
                (__attribute__((address_space(3))) void*)((char*)lA + (tid >> 6) * 1024), 16, 0, 0);
#pragma unroll
            for (int p = 0; p < 2; p++) {
                const uint16_t* gb = Bt + (size_t)(bn + p * 64 + srow) * C_DIM + kt + scol;
                __builtin_amdgcn_global_load_lds(
                    (const __attribute__((address_space(1))) void*)gb,
                    (__attribute__((address_space(3))) void*)((char*)lB + p * 4096 + (tid >> 6) * 1024), 16, 0, 0);
            }
        }
        __syncthreads();
        bf16x8 af[2], bfr[4];
#pragma unroll
        for (int i = 0; i < 2; i++)
            af[i]  = *reinterpret_cast<const bf16x8*>(&lA[(wm + i * 16 + rr) * 32 + pos]);
#pragma unroll
        for (int i = 0; i < 4; i++)
            bfr[i] = *reinterpret_cast<const bf16x8*>(&lB[(wn + i * 16 + rr) * 32 + pos]);
#pragma unroll
        for (int mi = 0; mi < 2; mi++)
#pragma unroll
            for (int ni = 0; ni < 4; ni++)
                acc[mi][ni] = __builtin_amdgcn_mfma_f32_16x16x32_bf16(af[mi], bfr[ni], acc[mi][ni], 0, 0, 0);
        __syncthreads();
    }

    const float* bias; uint16_t* outp; int coff, vmode;
    if (bn < 1024)      { bias = bq; outp = qb; coff = 0;    vmode = 0; }
    else if (bn < 2048) { bias = bk; outp = kb; coff = 1024; vmode = 0; }
    else                { bias = bv; outp = vt; coff = 2048; vmode = 1; }

    const int r0 = (lane >> 4) * 4;
    const int cc = lane & 15;
#pragma unroll
    for (int ni = 0; ni < 4; ni++) {
        const int colg = bn + wn + ni * 16 + cc;
        const int col = colg - coff;
        const float bvv = bias[col];
#pragma unroll
        for (int mi = 0; mi < 2; mi++) {
#pragma unroll
            for (int jj = 0; jj < 4; jj++) {
                const int row = bm + wm + mi * 16 + r0 + jj;
                float v = acc[mi][ni][jj] + bvv;
                if (vmode == 0) {
                    outp[(size_t)row * C_DIM + col] = f2bf(v);
                } else {
                    const int b = row >> 10, t2 = row & 1023;
                    const int h = col >> 6, d = col & 63;
                    outp[((size_t)((b * NH + h) * DH + d) << 10) + t2] = f2bf(v);
                }
            }
        }
    }
}

// ---------- output-proj GEMM: 64x128 tiles (512 blocks = 2/CU), BK=32, swizzled ----------
__global__ __launch_bounds__(256) void k_gemm_o(const uint16_t* __restrict__ A,
                                                const uint16_t* __restrict__ Bt,
                                                const float* __restrict__ bias,
                                                float* __restrict__ Out) {
    __shared__ uint16_t lA[64 * 32];
    __shared__ uint16_t lB[128 * 32];
    const int bm = blockIdx.x * 64;
    const int bn = blockIdx.y * 128;
    const int tid = threadIdx.x;
    const int lane = tid & 63;
    const int w = tid >> 6;
    const int wm = (w & 1) * 32;
    const int wn = (w >> 1) * 64;
    const int ko = (lane >> 4) * 8;
    const int rr = lane & 15;
    const int pos = ko ^ (((rr >> 1) & 3) << 3);

    f32x4 acc[2][4] = {};

    const int srow = tid >> 2;
    const int scol = (((tid & 3) ^ ((srow >> 1) & 3))) * 8;

    for (int kt = 0; kt < C_DIM; kt += 32) {
        {
            const uint16_t* ga = A + (size_t)(bm + (srow & 63)) * C_DIM + kt + scol;
            __builtin_amdgcn_global_load_lds(
                (const __attribute__((address_space(1))) void*)ga,
                (__attribute__((address_space(3))) void*)((char*)lA + (tid >> 6) * 1024), 16, 0, 0);
#pragma unroll
            for (int p = 0; p < 2; p++) {
                const uint16_t* gb = Bt + (size_t)(bn + p * 64 + srow) * C_DIM + kt + scol;
                __builtin_amdgcn_global_load_lds(
                    (const __attribute__((address_space(1))) void*)gb,
                    (__attribute__((address_space(3))) void*)((char*)lB + p * 4096 + (tid >> 6) * 1024), 16, 0, 0);
            }
        }
        __syncthreads();
        bf16x8 af[2], bfr[4];
#pragma unroll
        for (int i = 0; i < 2; i++)
            af[i]  = *reinterpret_cast<const bf16x8*>(&lA[(wm + i * 16 + rr) * 32 + pos]);
#pragma unroll
        for (int i = 0; i < 4; i++)
            bfr[i] = *reinterpret_cast<const bf16x8*>(&lB[(wn + i * 16 + rr) * 32 + pos]);
#pragma unroll
        for (int mi = 0; mi < 2; mi++)
#pragma unroll
            for (int ni = 0; ni < 4; ni++)
                acc[mi][ni] = __builtin_amdgcn_mfma_f32_16x16x32_bf16(af[mi], bfr[ni], acc[mi][ni], 0, 0, 0);
        __syncthreads();
    }

    const int r0 = (lane >> 4) * 4;
    const int cc = lane & 15;
#pragma unroll
    for (int ni = 0; ni < 4; ni++) {
        const int col = bn + wn + ni * 16 + cc;
        const float bvv = bias[col];
#pragma unroll
        for (int mi = 0; mi < 2; mi++)
#pragma unroll
            for (int jj = 0; jj < 4; jj++) {
                const int row = bm + wm + mi * 16 + r0 + jj;
                Out[(size_t)row * C_DIM + col] = acc[mi][ni][jj] + bvv;
            }
    }
}

// ---------- flash attention (R15/R17 best-measured): mega-tile K+V staged + diag h2-skip ----------
__global__ __launch_bounds__(256, 3) void k_attn(const uint16_t* __restrict__ Q,
                                                 const uint16_t* __restrict__ Kb,
                                                 const uint16_t* __restrict__ Vt,
                                                 const float* __restrict__ Vmean,
                                                 uint16_t* __restrict__ Ob) {
    __shared__ char smem[32768 + 4 * 4608];  // K 16KB | V 16KB | P per-wave lo/hi 2x2304B
    const int tid = threadIdx.x;
    const int lane = tid & 63;
    const int w = tid >> 6;
    uint16_t* lpLo = reinterpret_cast<uint16_t*>(smem + 32768 + w * 4608);
    uint16_t* lpHi = lpLo + 1152;

    const int id = blockIdx.x;
    const int bh = id & 63;
    const int braw = id >> 6;
    const int b = (braw < 4) ? braw : 11 - braw;
    const int q0 = b * 128;
    const int bb = bh >> 4, h = bh & 15;
    const int qq = lane & 15;
    const int gg = lane >> 4;
    const int ko = gg * 8;
    const int r0 = gg * 4;
    const int qgLo = q0 + w * 32 + qq;
    const int qgHi = qgLo + 16;

    const uint16_t* qpLo = Q + (size_t)(bb * T_SEQ + qgLo) * C_DIM + h * DH + ko;
    const uint16_t* qpHi = Q + (size_t)(bb * T_SEQ + qgHi) * C_DIM + h * DH + ko;
    bf16x8 bqLo0 = *reinterpret_cast<const bf16x8*>(qpLo);
    bf16x8 bqLo1 = *reinterpret_cast<const bf16x8*>(qpLo + 32);
    bf16x8 bqHi0 = *reinterpret_cast<const bf16x8*>(qpHi);
    bf16x8 bqHi1 = *reinterpret_cast<const bf16x8*>(qpHi + 32);

    const uint16_t* kbase = Kb + (size_t)bb * T_SEQ * C_DIM + h * DH;
    const uint16_t* vbase = Vt + (size_t)bh * DH * T_SEQ;
    const uint16_t* KL = reinterpret_cast<const uint16_t*>(smem);
    const uint16_t* VL = reinterpret_cast<const uint16_t*>(smem + 16384);

    f32x4 oLo[4] = {}, oHi[4] = {};
    float llLo = 0.f, llHi = 0.f;
    const float zs = 0.125f * 1.44269504088896f;

    const int sz = (qq & 7) << 3;

    const int t0 = b;
    for (int t = t0; t < 8; t++) {
        const int s0 = t * 128;
#pragma unroll
        for (int i = 0; i < 4; i++) {
            const int r = i * 32 + (tid >> 3);
            const int sc = ((tid & 7) ^ (r & 7)) * 8;
            const uint16_t* ks = kbase + (size_t)(s0 + r) * C_DIM + sc;
            __builtin_amdgcn_global_load_lds(
                (const __attribute__((address_space(1))) void*)ks,
                (__attribute__((address_space(3))) void*)(smem + i * 4096 + w * 1024), 16, 0, 0);
        }
#pragma unroll
        for (int i = 0; i < 4; i++) {
            const int r = i * 16 + (tid >> 4);
            const int sc = ((tid & 15) ^ (r & 7)) * 8;
            const uint16_t* vs = vbase + (size_t)r * T_SEQ + s0 + sc;
            __builtin_amdgcn_global_load_lds(
                (const __attribute__((address_space(1))) void*)vs,
                (__attribute__((address_space(3))) void*)(smem + 16384 + i * 4096 + w * 1024), 16, 0, 0);
        }
        __syncthreads();

        uint32_t* lpLo32 = reinterpret_cast<uint32_t*>(lpLo);
        uint32_t* lpHi32 = reinterpret_cast<uint32_t*>(lpHi);
#pragma unroll
        for (int h2 = 0; h2 < 2; h2++) {
            // diagonal mega-tile, low key-half: fully masked for waves 2,3 -> exact zeros
            if (t == t0 && h2 == 0 && w >= 2) continue;
#pragma unroll
            for (int hf = 0; hf < 4; hf++) {
                const int rr = h2 * 64 + hf * 16 + qq;
                bf16x8 kf0 = *reinterpret_cast<const bf16x8*>(&KL[rr * 64 + (ko ^ sz)]);
                bf16x8 kf1 = *reinterpret_cast<const bf16x8*>(&KL[rr * 64 + ((32 + ko) ^ sz)]);
                f32x4 sLo = {}, sHi = {};
                sLo = __builtin_amdgcn_mfma_f32_16x16x32_bf16(kf0, bqLo0, sLo, 0, 0, 0);
                sLo = __builtin_amdgcn_mfma_f32_16x16x32_bf16(kf1, bqLo1, sLo, 0, 0, 0);
                sHi = __builtin_amdgcn_mfma_f32_16x16x32_bf16(kf0, bqHi0, sHi, 0, 0, 0);
                sHi = __builtin_amdgcn_mfma_f32_16x16x32_bf16(kf1, bqHi1, sHi, 0, 0, 0);
#pragma unroll
                for (int j = 0; j < 4; j++) {
                    const int k = s0 + h2 * 64 + hf * 16 + r0 + j;
                    const float zLo = sLo[j] * zs + ((k <= qgLo) ? -1e9f : 0.0f);
                    const float zHi = sHi[j] * zs + ((k <= qgHi) ? -1e9f : 0.0f);
                    const float pLo = __builtin_amdgcn_exp2f(zLo);
                    const float pHi = __builtin_amdgcn_exp2f(zHi);
                    sLo[j] = pLo; llLo += pLo;
                    sHi[j] = pHi; llHi += pHi;
                }
#pragma unroll
                for (int jp = 0; jp < 2; jp++) {
                    union { __hip_bfloat162 h2u; uint32_t u; } cL, cH;
                    cL.h2u = __float22bfloat162_rn(make_float2(sLo[2 * jp], sLo[2 * jp + 1]));
                    cH.h2u = __float22bfloat162_rn(make_float2(sHi[2 * jp], sHi[2 * jp + 1]));
                    lpLo32[qq * 36 + hf * 8 + (r0 >> 1) + jp] = cL.u;
                    lpHi32[qq * 36 + hf * 8 + (r0 >> 1) + jp] = cH.u;
                }
            }
            bf16x8 paLo0 = *reinterpret_cast<const bf16x8*>(&lpLo[qq * 72 + ko]);
            bf16x8 paLo1 = *reinterpret_cast<const bf16x8*>(&lpLo[qq * 72 + 32 + ko]);
            bf16x8 paHi0 = *reinterpret_cast<const bf16x8*>(&lpHi[qq * 72 + ko]);
            bf16x8 paHi1 = *reinterpret_cast<const bf16x8*>(&lpHi[qq * 72 + 32 + ko]);
#pragma unroll
            for (int ni = 0; ni < 4; ni++) {
                const int rr = ni * 16 + qq;
                bf16x8 vf0 = *reinterpret_cast<const bf16x8*>(&VL[rr * 128 + ((h2 * 64 + ko) ^ sz)]);
                bf16x8 vf1 = *reinterpret_cast<const bf16x8*>(&VL[rr * 128 + ((h2 * 64 + 32 + ko) ^ sz)]);
                oLo[ni] = __builtin_amdgcn_mfma_f32_16x16x32_bf16(paLo0, vf0, oLo[ni], 0, 0, 0);
                oLo[ni] = __builtin_amdgcn_mfma_f32_16x16x32_bf16(paLo1, vf1, oLo[ni], 0, 0, 0);
                oHi[ni] = __builtin_amdgcn_mfma_f32_16x16x32_bf16(paHi0, vf0, oHi[ni], 0, 0, 0);
                oHi[ni] = __builtin_amdgcn_mfma_f32_16x16x32_bf16(paHi1, vf1, oHi[ni], 0, 0, 0);
            }
        }
        __syncthreads();
    }

    llLo += __shfl_xor(llLo, 16); llLo += __shfl_xor(llLo, 32);
    llHi += __shfl_xor(llHi, 16); llHi += __shfl_xor(llHi, 32);
#pragma unroll
    for (int j = 0; j < 4; j++) {
        {
            const float lr = __shfl(llLo, r0 + j);
            const size_t row = (size_t)(bb * T_SEQ + q0 + w * 32 + r0 + j);
            if (lr > 0.f) {
                const float rinv = 1.0f / lr;
#pragma unroll
                for (int ni = 0; ni < 4; ni++)
                    Ob[row * C_DIM + h * DH + ni * 16 + qq] = f2bf(oLo[ni][j] * rinv);
            } else {
#pragma unroll
                for (int ni = 0; ni < 4; ni++)
                    Ob[row * C_DIM + h * DH + ni * 16 + qq] = f2bf(Vmean[bh * DH + ni * 16 + qq]);
            }
        }
        {
            const float lr = __shfl(llHi, r0 + j);
            const size_t row = (size_t)(bb * T_SEQ + q0 + w * 32 + 16 + r0 + j);
            if (lr > 0.f) {
                const float rinv = 1.0f / lr;
#pragma unroll
                for (int ni = 0; ni < 4; ni++)
                    Ob[row * C_DIM + h * DH + ni * 16 + qq] = f2bf(oHi[ni][j] * rinv);
            } else {
                // fully-masked row (row 1023): reference softmax uniform -> mean of V
#pragma unroll
                for (int ni = 0; ni < 4; ni++)
                    Ob[row * C_DIM + h * DH + ni * 16 + qq] = f2bf(Vmean[bh * DH + ni * 16 + qq]);
            }
        }
    }
}

extern "C" void kernel_launch(void* const* d_in, const int* in_sizes, int n_in,
                              void* d_out, int out_size, void* d_ws, size_t ws_size,
                              hipStream_t stream) {
    const float* x  = (const float*)d_in[0];
    const float* Wq = (const float*)d_in[1];
    const float* bq = (const float*)d_in[2];
    const float* Wk = (const float*)d_in[3];
    const float* bk = (const float*)d_in[4];
    const float* Wv = (const float*)d_in[5];
    const float* bv = (const float*)d_in[6];
    const float* Wo = (const float*)d_in[7];
    const float* bo = (const float*)d_in[8];
    float* out = (float*)d_out;

    char* ws = (char*)d_ws;
    uint16_t* xb    = (uint16_t*)(ws);               // 8 MB
    uint16_t* wqkvt = (uint16_t*)(ws + (8u  << 20)); // 8 MB: Wq,Wk,Wv,Wo transposed bf16
    float*    vmean = (float*)   (ws + (12u << 20)); // 16 KB (hole in ws map)
    uint16_t* qb    = (uint16_t*)(ws + (16u << 20)); // 8 MB
    uint16_t* kb    = (uint16_t*)(ws + (24u << 20)); // 8 MB
    uint16_t* vt    = (uint16_t*)(ws + (32u << 20)); // 8 MB
    uint16_t* wot   = wqkvt + (3u << 20);
    uint16_t* ab    = qb;  // attn out aliases qb: each wave reads its own q rows before writing them

    k_prep<<<6144, 256, 0, stream>>>(x, Wq, Wk, Wv, Wo, xb, wqkvt);

    k_gemm_qkv<<<dim3(64, 24), 256, 0, stream>>>(xb, wqkvt, bq, bk, bv, qb, kb, vt);
    k_vmean<<<64, 256, 0, stream>>>(vt, vmean);
    k_attn<<<512, 256, 0, stream>>>(qb, kb, vt, vmean, ab);
    k_gemm_o<<<dim3(64, 8), 256, 0, stream>>>(ab, wot, bo, out);
}

// Round 20
// 100.249 us; speedup vs baseline: 1.1893x; 1.1893x over previous
//
#include <hip/hip_runtime.h>
#include <hip/hip_bf16.h>
#include <stdint.h>

#define T_SEQ 1024
#define C_DIM 1024
#define NH 16
#define DH 64

typedef __attribute__((ext_vector_type(8))) __bf16 bf16x8;
typedef __attribute__((ext_vector_type(8))) uint16_t u16x8;
typedef __attribute__((ext_vector_type(4))) float f32x4;

__device__ __forceinline__ uint16_t f2bf(float f) {
    union { float f; uint32_t u; } v; v.f = f;
    uint32_t u = v.u;
    return (uint16_t)((u + 0x7FFFu + ((u >> 16) & 1u)) >> 16);
}
__device__ __forceinline__ float bf2f(uint16_t b) {
    union { uint32_t u; float f; } v; v.u = ((uint32_t)b) << 16; return v.f;
}

// ---------- fused prep: cast x (blocks 0-2047) + transpose 4 weights (2048-6143) ----------
__global__ void k_prep(const float* __restrict__ x,
                       const float* __restrict__ W0, const float* __restrict__ W1,
                       const float* __restrict__ W2, const float* __restrict__ W3,
                       uint16_t* __restrict__ xb, uint16_t* __restrict__ wout) {
    const int gid = blockIdx.x;
    if (gid < 2048) {
        int i = gid * 256 + threadIdx.x;
        const int st = 2048 * 256;
#pragma unroll
        for (int it = 0; it < 2; it++, i += st) {
            float4 v = reinterpret_cast<const float4*>(x)[i];
            ushort4 o;
            o.x = f2bf(v.x); o.y = f2bf(v.y); o.z = f2bf(v.z); o.w = f2bf(v.w);
            reinterpret_cast<ushort4*>(xb)[i] = o;
        }
        return;
    }
    __shared__ float tile[32][33];
    const int id2 = gid - 2048;
    const int z = id2 >> 10;
    const int by = ((id2 >> 5) & 31) * 32;   // k block
    const int bx = (id2 & 31) * 32;          // n block
    const float* in = (z == 0) ? W0 : (z == 1) ? W1 : (z == 2) ? W2 : W3;
    uint16_t* o = wout + ((size_t)z << 20);
    const int tx = threadIdx.x & 31, ty = threadIdx.x >> 5;
#pragma unroll
    for (int i = 0; i < 4; i++)
        tile[ty + i * 8][tx] = in[(size_t)(by + ty + i * 8) * C_DIM + bx + tx];
    __syncthreads();
#pragma unroll
    for (int i = 0; i < 4; i++)
        o[(size_t)(bx + ty + i * 8) * C_DIM + by + tx] = f2bf(tile[tx][ty + i * 8]);
}

// ---------- V column mean (uniform-softmax fallback for fully-masked rows) ----------
__global__ void k_vmean(const uint16_t* __restrict__ Vt, float* __restrict__ Vmean) {
    const int bh = blockIdx.x;
    const int tid = threadIdx.x;
    const int d = tid >> 2, part = tid & 3;
    const uint16_t* src = Vt + ((size_t)bh * DH + d) * T_SEQ + part * 256;
    float s = 0.f;
#pragma unroll
    for (int i = 0; i < 32; i++) {
        u16x8 v = *reinterpret_cast<const u16x8*>(src + i * 8);
#pragma unroll
        for (int j = 0; j < 8; j++) s += bf2f(v[j]);
    }
    s += __shfl_xor(s, 1);
    s += __shfl_xor(s, 2);
    if (part == 0) Vmean[bh * DH + d] = s * (1.0f / 1024.0f);
}

// ---------- GEMM staging BK=32 with 2-way-optimal swizzle (R12-verified) ----------
// Phys slot (row r, chunk c) holds global chunk c ^ ((r>>1)&3). Read applies same XOR.
__device__ __forceinline__ void stage_g(const uint16_t* A, const uint16_t* Bt, int bm, int bn,
                                        int kt, char* la, char* lb, int tid) {
    const int w = tid >> 6, srow = tid >> 2;
    const int scol = (((tid & 3) ^ ((srow >> 1) & 3))) * 8;
#pragma unroll
    for (int p = 0; p < 2; p++) {
        const uint16_t* ga = A + (size_t)(bm + p * 64 + srow) * C_DIM + kt + scol;
        const uint16_t* gb = Bt + (size_t)(bn + p * 64 + srow) * C_DIM + kt + scol;
        __builtin_amdgcn_global_load_lds(
            (const __attribute__((address_space(1))) void*)ga,
            (__attribute__((address_space(3))) void*)(la + p * 4096 + w * 1024), 16, 0, 0);
        __builtin_amdgcn_global_load_lds(
            (const __attribute__((address_space(1))) void*)gb,
            (__attribute__((address_space(3))) void*)(lb + p * 4096 + w * 1024), 16, 0, 0);
    }
}

// ---------- fused QKV GEMM (R12: BK=32, 2-barrier, swizzled, 2D grid, 128x128) ----------
__global__ __launch_bounds__(256) void k_gemm_qkv(const uint16_t* __restrict__ A,
                                                  const uint16_t* __restrict__ Bt,
                                                  const float* __restrict__ bq,
                                                  const float* __restrict__ bk,
                                                  const float* __restrict__ bv,
                                                  uint16_t* __restrict__ qb,
                                                  uint16_t* __restrict__ kb,
                                                  uint16_t* __restrict__ vt) {
    __shared__ uint16_t lA[128 * 32];
    __shared__ uint16_t lB[128 * 32];
    const int bm = blockIdx.x * 128;
    const int bn = blockIdx.y * 128;
    const int tid = threadIdx.x;
    const int lane = tid & 63;
    const int w = tid >> 6;
    const int wm = (w >> 1) * 64;
    const int wn = (w & 1) * 64;
    const int ko = (lane >> 4) * 8;
    const int rr = lane & 15;
    const int pos = ko ^ (((rr >> 1) & 3) << 3);

    f32x4 acc[4][4] = {};

    for (int kt = 0; kt < C_DIM; kt += 32) {
        stage_g(A, Bt, bm, bn, kt, (char*)lA, (char*)lB, tid);
        __syncthreads();
        bf16x8 af[4], bfr[4];
#pragma unroll
        for (int i = 0; i < 4; i++) {
            af[i]  = *reinterpret_cast<const bf16x8*>(&lA[(wm + i * 16 + rr) * 32 + pos]);
            bfr[i] = *reinterpret_cast<const bf16x8*>(&lB[(wn + i * 16 + rr) * 32 + pos]);
        }
#pragma unroll
        for (int mi = 0; mi < 4; mi++)
#pragma unroll
            for (int ni = 0; ni < 4; ni++)
                acc[mi][ni] = __builtin_amdgcn_mfma_f32_16x16x32_bf16(af[mi], bfr[ni], acc[mi][ni], 0, 0, 0);
        __syncthreads();
    }

    const float* bias; uint16_t* outp; int coff, vmode;
    if (bn < 1024)      { bias = bq; outp = qb; coff = 0;    vmode = 0; }
    else if (bn < 2048) { bias = bk; outp = kb; coff = 1024; vmode = 0; }
    else                { bias = bv; outp = vt; coff = 2048; vmode = 1; }

    const int r0 = (lane >> 4) * 4;
    const int cc = lane & 15;
#pragma unroll
    for (int ni = 0; ni < 4; ni++) {
        const int colg = bn + wn + ni * 16 + cc;
        const int col = colg - coff;
        const float bvv = bias[col];
#pragma unroll
        for (int mi = 0; mi < 4; mi++) {
#pragma unroll
            for (int jj = 0; jj < 4; jj++) {
                const int row = bm + wm + mi * 16 + r0 + jj;
                float v = acc[mi][ni][jj] + bvv;
                if (vmode == 0) {
                    outp[(size_t)row * C_DIM + col] = f2bf(v);
                } else {
                    const int b = row >> 10, t2 = row & 1023;
                    const int h = col >> 6, d = col & 63;
                    outp[((size_t)((b * NH + h) * DH + d) << 10) + t2] = f2bf(v);
                }
            }
        }
    }
}

// ---------- output-proj GEMM: 64x128 tiles (512 blocks = 2/CU), BK=32, swizzled ----------
__global__ __launch_bounds__(256) void k_gemm_o(const uint16_t* __restrict__ A,
                                                const uint16_t* __restrict__ Bt,
                                                const float* __restrict__ bias,
                                                float* __restrict__ Out) {
    __shared__ uint16_t lA[64 * 32];
    __shared__ uint16_t lB[128 * 32];
    const int bm = blockIdx.x * 64;
    const int bn = blockIdx.y * 128;
    const int tid = threadIdx.x;
    const int lane = tid & 63;
    const int w = tid >> 6;
    const int wm = (w & 1) * 32;
    const int wn = (w >> 1) * 64;
    const int ko = (lane >> 4) * 8;
    const int rr = lane & 15;
    const int pos = ko ^ (((rr >> 1) & 3) << 3);

    f32x4 acc[2][4] = {};

    const int srow = tid >> 2;
    const int scol = (((tid & 3) ^ ((srow >> 1) & 3))) * 8;

    for (int kt = 0; kt < C_DIM; kt += 32) {
        {
            const uint16_t* ga = A + (size_t)(bm + (srow & 63)) * C_DIM + kt + scol;
            __builtin_amdgcn_global_load_lds(
                (const __attribute__((address_space(1))) void*)ga,
                (__attribute__((address_space(3))) void*)((char*)lA + (tid >> 6) * 1024), 16, 0, 0);
#pragma unroll
            for (int p = 0; p < 2; p++) {
                const uint16_t* gb = Bt + (size_t)(bn + p * 64 + srow) * C_DIM + kt + scol;
                __builtin_amdgcn_global_load_lds(
                    (const __attribute__((address_space(1))) void*)gb,
                    (__attribute__((address_space(3))) void*)((char*)lB + p * 4096 + (tid >> 6) * 1024), 16, 0, 0);
            }
        }
        __syncthreads();
        bf16x8 af[2], bfr[4];
#pragma unroll
        for (int i = 0; i < 2; i++)
            af[i]  = *reinterpret_cast<const bf16x8*>(&lA[(wm + i * 16 + rr) * 32 + pos]);
#pragma unroll
        for (int i = 0; i < 4; i++)
            bfr[i] = *reinterpret_cast<const bf16x8*>(&lB[(wn + i * 16 + rr) * 32 + pos]);
#pragma unroll
        for (int mi = 0; mi < 2; mi++)
#pragma unroll
            for (int ni = 0; ni < 4; ni++)
                acc[mi][ni] = __builtin_amdgcn_mfma_f32_16x16x32_bf16(af[mi], bfr[ni], acc[mi][ni], 0, 0, 0);
        __syncthreads();
    }

    const int r0 = (lane >> 4) * 4;
    const int cc = lane & 15;
#pragma unroll
    for (int ni = 0; ni < 4; ni++) {
        const int col = bn + wn + ni * 16 + cc;
        const float bvv = bias[col];
#pragma unroll
        for (int mi = 0; mi < 2; mi++)
#pragma unroll
            for (int jj = 0; jj < 4; jj++) {
                const int row = bm + wm + mi * 16 + r0 + jj;
                Out[(size_t)row * C_DIM + col] = acc[mi][ni][jj] + bvv;
            }
    }
}

// ---------- flash attention (R15/R17 best-measured): mega-tile K+V staged + diag h2-skip ----------
__global__ __launch_bounds__(256, 3) void k_attn(const uint16_t* __restrict__ Q,
                                                 const uint16_t* __restrict__ Kb,
                                                 const uint16_t* __restrict__ Vt,
                                                 const float* __restrict__ Vmean,
                                                 uint16_t* __restrict__ Ob) {
    __shared__ char smem[32768 + 4 * 4608];  // K 16KB | V 16KB | P per-wave lo/hi 2x2304B
    const int tid = threadIdx.x;
    const int lane = tid & 63;
    const int w = tid >> 6;
    uint16_t* lpLo = reinterpret_cast<uint16_t*>(smem + 32768 + w * 4608);
    uint16_t* lpHi = lpLo + 1152;

    const int id = blockIdx.x;
    const int bh = id & 63;
    const int braw = id >> 6;
    const int b = (braw < 4) ? braw : 11 - braw;
    const int q0 = b * 128;
    const int bb = bh >> 4, h = bh & 15;
    const int qq = lane & 15;
    const int gg = lane >> 4;
    const int ko = gg * 8;
    const int r0 = gg * 4;
    const int qgLo = q0 + w * 32 + qq;
    const int qgHi = qgLo + 16;

    const uint16_t* qpLo = Q + (size_t)(bb * T_SEQ + qgLo) * C_DIM + h * DH + ko;
    const uint16_t* qpHi = Q + (size_t)(bb * T_SEQ + qgHi) * C_DIM + h * DH + ko;
    bf16x8 bqLo0 = *reinterpret_cast<const bf16x8*>(qpLo);
    bf16x8 bqLo1 = *reinterpret_cast<const bf16x8*>(qpLo + 32);
    bf16x8 bqHi0 = *reinterpret_cast<const bf16x8*>(qpHi);
    bf16x8 bqHi1 = *reinterpret_cast<const bf16x8*>(qpHi + 32);

    const uint16_t* kbase = Kb + (size_t)bb * T_SEQ * C_DIM + h * DH;
    const uint16_t* vbase = Vt + (size_t)bh * DH * T_SEQ;
    const uint16_t* KL = reinterpret_cast<const uint16_t*>(smem);
    const uint16_t* VL = reinterpret_cast<const uint16_t*>(smem + 16384);

    f32x4 oLo[4] = {}, oHi[4] = {};
    float llLo = 0.f, llHi = 0.f;
    const float zs = 0.125f * 1.44269504088896f;

    const int sz = (qq & 7) << 3;

    const int t0 = b;
    for (int t = t0; t < 8; t++) {
        const int s0 = t * 128;
#pragma unroll
        for (int i = 0; i < 4; i++) {
            const int r = i * 32 + (tid >> 3);
            const int sc = ((tid & 7) ^ (r & 7)) * 8;
            const uint16_t* ks = kbase + (size_t)(s0 + r) * C_DIM + sc;
            __builtin_amdgcn_global_load_lds(
                (const __attribute__((address_space(1))) void*)ks,
                (__attribute__((address_space(3))) void*)(smem + i * 4096 + w * 1024), 16, 0, 0);
        }
#pragma unroll
        for (int i = 0; i < 4; i++) {
            const int r = i * 16 + (tid >> 4);
            const int sc = ((tid & 15) ^ (r & 7)) * 8;
            const uint16_t* vs = vbase + (size_t)r * T_SEQ + s0 + sc;
            __builtin_amdgcn_global_load_lds(
                (const __attribute__((address_space(1))) void*)vs,
                (__attribute__((address_space(3))) void*)(smem + 16384 + i * 4096 + w * 1024), 16, 0, 0);
        }
        __syncthreads();

        uint32_t* lpLo32 = reinterpret_cast<uint32_t*>(lpLo);
        uint32_t* lpHi32 = reinterpret_cast<uint32_t*>(lpHi);
#pragma unroll
        for (int h2 = 0; h2 < 2; h2++) {
            // diagonal mega-tile, low key-half: fully masked for waves 2,3 -> exact zeros
            if (t == t0 && h2 == 0 && w >= 2) continue;
#pragma unroll
            for (int hf = 0; hf < 4; hf++) {
                const int rr = h2 * 64 + hf * 16 + qq;
                bf16x8 kf0 = *reinterpret_cast<const bf16x8*>(&KL[rr * 64 + (ko ^ sz)]);
                bf16x8 kf1 = *reinterpret_cast<const bf16x8*>(&KL[rr * 64 + ((32 + ko) ^ sz)]);
                f32x4 sLo = {}, sHi = {};
                sLo = __builtin_amdgcn_mfma_f32_16x16x32_bf16(kf0, bqLo0, sLo, 0, 0, 0);
                sLo = __builtin_amdgcn_mfma_f32_16x16x32_bf16(kf1, bqLo1, sLo, 0, 0, 0);
                sHi = __builtin_amdgcn_mfma_f32_16x16x32_bf16(kf0, bqHi0, sHi, 0, 0, 0);
                sHi = __builtin_amdgcn_mfma_f32_16x16x32_bf16(kf1, bqHi1, sHi, 0, 0, 0);
#pragma unroll
                for (int j = 0; j < 4; j++) {
                    const int k = s0 + h2 * 64 + hf * 16 + r0 + j;
                    const float zLo = sLo[j] * zs + ((k <= qgLo) ? -1e9f : 0.0f);
                    const float zHi = sHi[j] * zs + ((k <= qgHi) ? -1e9f : 0.0f);
                    const float pLo = __builtin_amdgcn_exp2f(zLo);
                    const float pHi = __builtin_amdgcn_exp2f(zHi);
                    sLo[j] = pLo; llLo += pLo;
                    sHi[j] = pHi; llHi += pHi;
                }
#pragma unroll
                for (int jp = 0; jp < 2; jp++) {
                    union { __hip_bfloat162 h2u; uint32_t u; } cL, cH;
                    cL.h2u = __float22bfloat162_rn(make_float2(sLo[2 * jp], sLo[2 * jp + 1]));
                    cH.h2u = __float22bfloat162_rn(make_float2(sHi[2 * jp], sHi[2 * jp + 1]));
                    lpLo32[qq * 36 + hf * 8 + (r0 >> 1) + jp] = cL.u;
                    lpHi32[qq * 36 + hf * 8 + (r0 >> 1) + jp] = cH.u;
                }
            }
            bf16x8 paLo0 = *reinterpret_cast<const bf16x8*>(&lpLo[qq * 72 + ko]);
            bf16x8 paLo1 = *reinterpret_cast<const bf16x8*>(&lpLo[qq * 72 + 32 + ko]);
            bf16x8 paHi0 = *reinterpret_cast<const bf16x8*>(&lpHi[qq * 72 + ko]);
            bf16x8 paHi1 = *reinterpret_cast<const bf16x8*>(&lpHi[qq * 72 + 32 + ko]);
#pragma unroll
            for (int ni = 0; ni < 4; ni++) {
                const int rr = ni * 16 + qq;
                bf16x8 vf0 = *reinterpret_cast<const bf16x8*>(&VL[rr * 128 + ((h2 * 64 + ko) ^ sz)]);
                bf16x8 vf1 = *reinterpret_cast<const bf16x8*>(&VL[rr * 128 + ((h2 * 64 + 32 + ko) ^ sz)]);
                oLo[ni] = __builtin_amdgcn_mfma_f32_16x16x32_bf16(paLo0, vf0, oLo[ni], 0, 0, 0);
                oLo[ni] = __builtin_amdgcn_mfma_f32_16x16x32_bf16(paLo1, vf1, oLo[ni], 0, 0, 0);
                oHi[ni] = __builtin_amdgcn_mfma_f32_16x16x32_bf16(paHi0, vf0, oHi[ni], 0, 0, 0);
                oHi[ni] = __builtin_amdgcn_mfma_f32_16x16x32_bf16(paHi1, vf1, oHi[ni], 0, 0, 0);
            }
        }
        __syncthreads();
    }

    llLo += __shfl_xor(llLo, 16); llLo += __shfl_xor(llLo, 32);
    llHi += __shfl_xor(llHi, 16); llHi += __shfl_xor(llHi, 32);
#pragma unroll
    for (int j = 0; j < 4; j++) {
        {
            const float lr = __shfl(llLo, r0 + j);
            const size_t row = (size_t)(bb * T_SEQ + q0 + w * 32 + r0 + j);
            if (lr > 0.f) {
                const float rinv = 1.0f / lr;
#pragma unroll
                for (int ni = 0; ni < 4; ni++)
                    Ob[row * C_DIM + h * DH + ni * 16 + qq] = f2bf(oLo[ni][j] * rinv);
            } else {
#pragma unroll
                for (int ni = 0; ni < 4; ni++)
                    Ob[row * C_DIM + h * DH + ni * 16 + qq] = f2bf(Vmean[bh * DH + ni * 16 + qq]);
            }
        }
        {
            const float lr = __shfl(llHi, r0 + j);
            const size_t row = (size_t)(bb * T_SEQ + q0 + w * 32 + 16 + r0 + j);
            if (lr > 0.f) {
                const float rinv = 1.0f / lr;
#pragma unroll
                for (int ni = 0; ni < 4; ni++)
                    Ob[row * C_DIM + h * DH + ni * 16 + qq] = f2bf(oHi[ni][j] * rinv);
            } else {
                // fully-masked row (row 1023): reference softmax uniform -> mean of V
#pragma unroll
                for (int ni = 0; ni < 4; ni++)
                    Ob[row * C_DIM + h * DH + ni * 16 + qq] = f2bf(Vmean[bh * DH + ni * 16 + qq]);
            }
        }
    }
}

extern "C" void kernel_launch(void* const* d_in, const int* in_sizes, int n_in,
                              void* d_out, int out_size, void* d_ws, size_t ws_size,
                              hipStream_t stream) {
    const float* x  = (const float*)d_in[0];
    const float* Wq = (const float*)d_in[1];
    const float* bq = (const float*)d_in[2];
    const float* Wk = (const float*)d_in[3];
    const float* bk = (const float*)d_in[4];
    const float* Wv = (const float*)d_in[5];
    const float* bv = (const float*)d_in[6];
    const float* Wo = (const float*)d_in[7];
    const float* bo = (const float*)d_in[8];
    float* out = (float*)d_out;

    char* ws = (char*)d_ws;
    uint16_t* xb    = (uint16_t*)(ws);               // 8 MB
    uint16_t* wqkvt = (uint16_t*)(ws + (8u  << 20)); // 8 MB: Wq,Wk,Wv,Wo transposed bf16
    float*    vmean = (float*)   (ws + (12u << 20)); // 16 KB (hole in ws map)
    uint16_t* qb    = (uint16_t*)(ws + (16u << 20)); // 8 MB
    uint16_t* kb    = (uint16_t*)(ws + (24u << 20)); // 8 MB
    uint16_t* vt    = (uint16_t*)(ws + (32u << 20)); // 8 MB
    uint16_t* wot   = wqkvt + (3u << 20);
    uint16_t* ab    = qb;  // attn out aliases qb: each wave reads its own q rows before writing them

    k_prep<<<6144, 256, 0, stream>>>(x, Wq, Wk, Wv, Wo, xb, wqkvt);

    k_gemm_qkv<<<dim3(32, 24), 256, 0, stream>>>(xb, wqkvt, bq, bk, bv, qb, kb, vt);
    k_vmean<<<64, 256, 0, stream>>>(vt, vmean);
    k_attn<<<512, 256, 0, stream>>>(qb, kb, vt, vmean, ab);
    k_gemm_o<<<dim3(64, 8), 256, 0, stream>>>(ab, wot, bo, out);
}